// Round 3
// baseline (151.646 us; speedup 1.0000x reference)
//
#include <hip/hip_runtime.h>
#include <hip/hip_bf16.h>

// Problem constants
#define B 64
#define S 512
#define D 768
#define K 8
#define R 277
#define NSPAN 10     // h, t, 8 bridge spans per batch
#define M_TOT 640    // pooled rows: [u: 0..63][v: 64..127][bi: 128..639]

// ---------------------------------------------------------------------------
// Pool phase 1: one block per (batch b, s-chunk c). For each span, loop over
// (span ∩ chunk) rows with a branch-free load+fmax body (short, unrollable,
// loads pipelined). Rows shared by multiple spans re-read from L2 (chunk is
// 48 KB, L2-resident) so HBM traffic ~= union of spans (~one pass over emb).
// 192 threads; thread t owns float4 slot t of the 768-dim row.
// ---------------------------------------------------------------------------
__global__ void k_pool1(const float* __restrict__ emb,
                        const int* __restrict__ h_span,
                        const int* __restrict__ t_span,
                        const int* __restrict__ b_spans,
                        float* __restrict__ partial, int nch) {
    int b = blockIdx.x, c = blockIdx.y;
    int rpc = S / nch;
    int r0 = c * rpc, r1 = r0 + rpc;       // [r0, r1)
    int t = threadIdx.x;

    int s0[NSPAN], s1[NSPAN];
    s0[0] = h_span[b*2]; s1[0] = h_span[b*2+1];
    s0[1] = t_span[b*2]; s1[1] = t_span[b*2+1];
    #pragma unroll
    for (int k = 0; k < K; ++k) {
        s0[2+k] = b_spans[(b*K+k)*2];
        s1[2+k] = b_spans[(b*K+k)*2 + 1];
    }

    const float4* e4 = (const float4*)(emb + (size_t)b * S * D);
    #pragma unroll
    for (int j = 0; j < NSPAN; ++j) {
        int a = s0[j] > r0 ? s0[j] : r0;
        int e = (s1[j] + 1) < r1 ? (s1[j] + 1) : r1;
        if (a >= e) continue;              // uniform: span misses this chunk
        float4 m = make_float4(-INFINITY, -INFINITY, -INFINITY, -INFINITY);
        #pragma unroll 4
        for (int s = a; s < e; ++s) {
            float4 v = e4[(size_t)s * (D/4) + t];
            m.x = fmaxf(m.x, v.x); m.y = fmaxf(m.y, v.y);
            m.z = fmaxf(m.z, v.z); m.w = fmaxf(m.w, v.w);
        }
        *(float4*)(partial + (((size_t)(b*nch + c))*NSPAN + j) * D + t*4) = m;
    }
}

// ---------------------------------------------------------------------------
// Pool phase 2: one block per (b, span j). Reduces only the chunks that
// intersect the span (recomputed from inputs — untouched partials never read).
// ---------------------------------------------------------------------------
__global__ void k_pool2(const float* __restrict__ partial,
                        const int* __restrict__ h_span,
                        const int* __restrict__ t_span,
                        const int* __restrict__ b_spans,
                        float* __restrict__ pooled, int nch) {
    int task = blockIdx.x;             // 0..639
    int b = task / NSPAN, j = task % NSPAN;
    int s0, s1, row;
    if (j == 0)      { s0 = h_span[b*2]; s1 = h_span[b*2+1]; row = b; }
    else if (j == 1) { s0 = t_span[b*2]; s1 = t_span[b*2+1]; row = B + b; }
    else {
        int k = j - 2;
        s0 = b_spans[(b*K+k)*2]; s1 = b_spans[(b*K+k)*2 + 1];
        row = 2*B + b*K + k;
    }
    int rpc = S / nch;
    int c0 = s0 / rpc, c1 = s1 / rpc;
    int t = threadIdx.x;
    float4 m = make_float4(-INFINITY, -INFINITY, -INFINITY, -INFINITY);
    for (int c = c0; c <= c1; ++c) {
        float4 v = *(const float4*)(partial + (((size_t)(b*nch + c))*NSPAN + j) * D + t*4);
        m.x = fmaxf(m.x, v.x); m.y = fmaxf(m.y, v.y);
        m.z = fmaxf(m.z, v.z); m.w = fmaxf(m.w, v.w);
    }
    ((float4*)(pooled + (size_t)row * D))[t] = m;
}

// ---------------------------------------------------------------------------
// GEMM: p_part[ks][m][e] = sum_{d in ks-range} pooled[m][d] * W_m[e][d]
// 64x64 tiles, 4x4 register tiles, both operands staged transposed in LDS.
// grid = (12, 10, ksplit), block = 256.
// ---------------------------------------------------------------------------
__global__ void k_gemm(const float* __restrict__ pooled,
                       const float* __restrict__ wu,
                       const float* __restrict__ wv,
                       const float* __restrict__ wi,
                       float* __restrict__ p_part, int ksplit) {
    __shared__ float At[16][68];
    __shared__ float Wt[16][68];
    int e0 = blockIdx.x * 64;
    int m0 = blockIdx.y * 64;
    int klen = D / ksplit;
    int dbase = blockIdx.z * klen;
    const float* Wm = (m0 < B) ? wu : (m0 < 2*B) ? wv : wi;

    int tid = threadIdx.x;
    int tx = tid & 15, ty = tid >> 4;
    int lm = tid >> 2;
    int ld = (tid & 3) * 4;

    float acc[4][4] = {};
    int kchunks = klen / 16;
    for (int kc = 0; kc < kchunks; ++kc) {
        int d0 = dbase + kc * 16;
        float4 a4 = *(const float4*)(pooled + (size_t)(m0 + lm) * D + d0 + ld);
        float4 w4 = *(const float4*)(Wm     + (size_t)(e0 + lm) * D + d0 + ld);
        __syncthreads();
        At[ld+0][lm] = a4.x; At[ld+1][lm] = a4.y; At[ld+2][lm] = a4.z; At[ld+3][lm] = a4.w;
        Wt[ld+0][lm] = w4.x; Wt[ld+1][lm] = w4.y; Wt[ld+2][lm] = w4.z; Wt[ld+3][lm] = w4.w;
        __syncthreads();
        #pragma unroll
        for (int dd = 0; dd < 16; ++dd) {
            float4 av  = *(const float4*)&At[dd][ty << 2];
            float4 wvv = *(const float4*)&Wt[dd][tx << 2];
            float a_[4] = {av.x, av.y, av.z, av.w};
            float w_[4] = {wvv.x, wvv.y, wvv.z, wvv.w};
            #pragma unroll
            for (int i = 0; i < 4; ++i)
                #pragma unroll
                for (int jj = 0; jj < 4; ++jj)
                    acc[i][jj] += a_[i] * w_[jj];
        }
    }
    #pragma unroll
    for (int i = 0; i < 4; ++i) {
        float4 o = make_float4(acc[i][0], acc[i][1], acc[i][2], acc[i][3]);
        *(float4*)(p_part + ((size_t)blockIdx.z * M_TOT + m0 + ty*4 + i) * D + e0 + tx*4) = o;
    }
}

// ---------------------------------------------------------------------------
// Attention + s = u + v + ctx. One block per b, 256 threads (192 active for
// float4 element work, all 4 waves for the dot products).
// ---------------------------------------------------------------------------
__global__ void k_att(const float* __restrict__ p_part,
                      const float* __restrict__ wu_b,
                      const float* __restrict__ wv_b,
                      const float* __restrict__ wi_b,
                      float* __restrict__ s_out, int ksplit) {
    __shared__ float U[D], V[D], BI[K][D];
    __shared__ float dots[K];
    int b = blockIdx.x, tid = threadIdx.x;

    if (tid < 192) {
        int t = tid;
        float4 su = *(const float4*)(wu_b + t*4);
        float4 sv = *(const float4*)(wv_b + t*4);
        for (int ks = 0; ks < ksplit; ++ks) {
            float4 pu = *(const float4*)(p_part + ((size_t)ks * M_TOT + b)     * D + t*4);
            float4 pv = *(const float4*)(p_part + ((size_t)ks * M_TOT + B + b) * D + t*4);
            su.x += pu.x; su.y += pu.y; su.z += pu.z; su.w += pu.w;
            sv.x += pv.x; sv.y += pv.y; sv.z += pv.z; sv.w += pv.w;
        }
        *(float4*)&U[t*4] = su;
        *(float4*)&V[t*4] = sv;
        #pragma unroll
        for (int k = 0; k < K; ++k) {
            float4 sb = *(const float4*)(wi_b + t*4);
            for (int ks = 0; ks < ksplit; ++ks) {
                float4 pb = *(const float4*)(p_part + ((size_t)ks * M_TOT + 2*B + b*K + k) * D + t*4);
                sb.x += pb.x; sb.y += pb.y; sb.z += pb.z; sb.w += pb.w;
            }
            *(float4*)&BI[k][t*4] = sb;
        }
    }
    __syncthreads();

    int wave = tid >> 6, lane = tid & 63;
    for (int kk = 0; kk < 2; ++kk) {
        int k = wave * 2 + kk;
        float part = 0.f;
        for (int d = lane; d < D; d += 64) part += U[d] * BI[k][d];
        #pragma unroll
        for (int off = 32; off > 0; off >>= 1) part += __shfl_down(part, off);
        if (lane == 0) dots[k] = part * 0.125f;   // 1/sqrt(D_K=64)
    }
    __syncthreads();

    float mx = -INFINITY;
    #pragma unroll
    for (int k = 0; k < K; ++k) mx = fmaxf(mx, dots[k]);
    float ex[K], sum = 0.f;
    #pragma unroll
    for (int k = 0; k < K; ++k) { ex[k] = expf(dots[k] - mx); sum += ex[k]; }
    float inv = 1.f / sum;

    for (int d = tid; d < D; d += 256) {
        float c = 0.f;
        #pragma unroll
        for (int k = 0; k < K; ++k) c += ex[k] * BI[k][d];
        s_out[(size_t)b * D + d] = U[d] + V[d] + c * inv;
    }
}

// ---------------------------------------------------------------------------
// pair = relu(s @ ln1_w^T + ln1_b). grid (3, 64), 256 thr, 1 out/thr.
// ---------------------------------------------------------------------------
__global__ void k_pair(const float* __restrict__ s,
                       const float* __restrict__ ln1_w,
                       const float* __restrict__ ln1_b,
                       float* __restrict__ pair) {
    __shared__ float Sv[D];
    int b = blockIdx.y, e0 = blockIdx.x * 256, tid = threadIdx.x;
    for (int d = tid; d < D; d += 256) Sv[d] = s[(size_t)b * D + d];
    __syncthreads();
    int e = e0 + tid;
    const float* wr = ln1_w + (size_t)e * D;
    float acc = 0.f;
    for (int d = 0; d < D; d += 4) {
        float4 s4 = *(const float4*)&Sv[d];
        float4 w4 = *(const float4*)(wr + d);
        acc += s4.x*w4.x + s4.y*w4.y + s4.z*w4.z + s4.w*w4.w;
    }
    pair[(size_t)b * D + e] = fmaxf(acc + ln1_b[e], 0.f);
}

// ---------------------------------------------------------------------------
// logits = pair @ pred_w^T + pred_b. One block per b, 320 thr.
// ---------------------------------------------------------------------------
__global__ void k_pred(const float* __restrict__ pair,
                       const float* __restrict__ pred_w,
                       const float* __restrict__ pred_b,
                       float* __restrict__ out) {
    __shared__ float P[D];
    int b = blockIdx.x, tid = threadIdx.x;
    for (int d = tid; d < D; d += 320) P[d] = pair[(size_t)b * D + d];
    __syncthreads();
    if (tid < R) {
        const float* wr = pred_w + (size_t)tid * D;
        float acc = 0.f;
        for (int d = 0; d < D; d += 4) {
            float4 p4 = *(const float4*)&P[d];
            float4 w4 = *(const float4*)(wr + d);
            acc += p4.x*w4.x + p4.y*w4.y + p4.z*w4.z + p4.w*w4.w;
        }
        out[(size_t)b * R + tid] = acc + pred_b[tid];
    }
}

// ---------------------------------------------------------------------------
extern "C" void kernel_launch(void* const* d_in, const int* in_sizes, int n_in,
                              void* d_out, int out_size, void* d_ws, size_t ws_size,
                              hipStream_t stream) {
    const float* emb     = (const float*)d_in[0];
    const int*   h_span  = (const int*)  d_in[1];
    const int*   t_span  = (const int*)  d_in[2];
    const int*   b_spans = (const int*)  d_in[3];
    const float* wu_w    = (const float*)d_in[4];
    const float* wu_b    = (const float*)d_in[5];
    const float* wv_w    = (const float*)d_in[6];
    const float* wv_b    = (const float*)d_in[7];
    const float* wi_w    = (const float*)d_in[8];
    const float* wi_b    = (const float*)d_in[9];
    const float* ln1_w   = (const float*)d_in[10];
    const float* ln1_b   = (const float*)d_in[11];
    const float* pred_w  = (const float*)d_in[12];
    const float* pred_b  = (const float*)d_in[13];
    float* out = (float*)d_out;

    // Pick the biggest (ksplit, nch) config that fits ws_size.
    size_t avail = ws_size / sizeof(float);
    int ksplit = 8, nch = 32;
    auto need = [&](int ks_, int nch_) -> size_t {
        return (size_t)M_TOT*D                  // pooled
             + (size_t)ks_*M_TOT*D              // p_part
             + 2*(size_t)B*D                    // s_buf + pair
             + (size_t)B*nch_*NSPAN*D;          // partial
    };
    while (nch > 2 && need(ksplit, nch) > avail) nch >>= 1;
    while (ksplit > 2 && need(ksplit, nch) > avail) ksplit >>= 1;

    float* ws      = (float*)d_ws;
    float* pooled  = ws;                                   // M_TOT*D
    float* p_part  = pooled + (size_t)M_TOT * D;           // ksplit*M_TOT*D
    float* s_buf   = p_part + (size_t)ksplit * M_TOT * D;  // B*D
    float* pair    = s_buf + (size_t)B * D;                // B*D
    float* partial = pair + (size_t)B * D;                 // B*nch*NSPAN*D

    k_pool1<<<dim3(B, nch), 192, 0, stream>>>(emb, h_span, t_span, b_spans, partial, nch);
    k_pool2<<<M_TOT, 192, 0, stream>>>(partial, h_span, t_span, b_spans, pooled, nch);
    k_gemm<<<dim3(D/64, M_TOT/64, ksplit), 256, 0, stream>>>(pooled, wu_w, wv_w, wi_w, p_part, ksplit);
    k_att<<<B, 256, 0, stream>>>(p_part, wu_b, wv_b, wi_b, s_buf, ksplit);
    k_pair<<<dim3(D/256, B), 256, 0, stream>>>(s_buf, ln1_w, ln1_b, pair);
    k_pred<<<B, 320, 0, stream>>>(pair, pred_w, pred_b, out);
}

// Round 4
// 108.149 us; speedup vs baseline: 1.4022x; 1.4022x over previous
//
#include <hip/hip_runtime.h>
#include <hip/hip_bf16.h>

// Problem constants
#define B 64
#define S 512
#define D 768
#define K 8
#define R 277
#define NSPAN 10     // h, t, 8 bridge spans per batch
#define M_TOT 640    // pooled rows: [u: 0..63][v: 64..127][bi: 128..639]

// ---------------------------------------------------------------------------
// Pool phase 1 (streaming, branchless): one block per (b, s-chunk). Streams
// ALL RPC rows of its chunk unconditionally (RPC independent float4 loads,
// fully unrolled -> deep MLP), updating all 10 span accumulators with
// select+fmax (no branches in the hot loop; work perfectly uniform).
// 192 threads; thread t owns float4 slot t of the 768-dim row.
// ---------------------------------------------------------------------------
template<int RPC>
__global__ void k_pool1(const float* __restrict__ emb,
                        const int* __restrict__ h_span,
                        const int* __restrict__ t_span,
                        const int* __restrict__ b_spans,
                        float* __restrict__ partial) {
    int b = blockIdx.x, c = blockIdx.y;
    int nch = S / RPC;
    int r0 = c * RPC;
    int t = threadIdx.x;

    int s0[NSPAN], s1[NSPAN];
    s0[0] = h_span[b*2]; s1[0] = h_span[b*2+1];
    s0[1] = t_span[b*2]; s1[1] = t_span[b*2+1];
    #pragma unroll
    for (int k = 0; k < K; ++k) {
        s0[2+k] = b_spans[(b*K+k)*2];
        s1[2+k] = b_spans[(b*K+k)*2 + 1];
    }

    float4 m[NSPAN];
    #pragma unroll
    for (int j = 0; j < NSPAN; ++j)
        m[j] = make_float4(-INFINITY, -INFINITY, -INFINITY, -INFINITY);

    const float4* e4 = (const float4*)(emb + (size_t)b * S * D) + (size_t)r0 * (D/4) + t;
    #pragma unroll
    for (int i = 0; i < RPC; ++i) {
        float4 v = e4[i * (D/4)];
        int s = r0 + i;
        #pragma unroll
        for (int j = 0; j < NSPAN; ++j) {
            bool in = (s >= s0[j]) && (s <= s1[j]);
            float vx = in ? v.x : -INFINITY;
            float vy = in ? v.y : -INFINITY;
            float vz = in ? v.z : -INFINITY;
            float vw = in ? v.w : -INFINITY;
            m[j].x = fmaxf(m[j].x, vx); m[j].y = fmaxf(m[j].y, vy);
            m[j].z = fmaxf(m[j].z, vz); m[j].w = fmaxf(m[j].w, vw);
        }
    }

    #pragma unroll
    for (int j = 0; j < NSPAN; ++j) {
        if (s1[j] >= r0 && s0[j] < r0 + RPC) {   // uniform: span intersects chunk
            *(float4*)(partial + (((size_t)(b*nch + c))*NSPAN + j) * D + t*4) = m[j];
        }
    }
}

// ---------------------------------------------------------------------------
// Pool phase 2: one block per (b, span j). Reduces only the chunks that
// intersect the span (recomputed from inputs — untouched partials never read).
// ---------------------------------------------------------------------------
__global__ void k_pool2(const float* __restrict__ partial,
                        const int* __restrict__ h_span,
                        const int* __restrict__ t_span,
                        const int* __restrict__ b_spans,
                        float* __restrict__ pooled, int rpc) {
    int task = blockIdx.x;             // 0..639
    int b = task / NSPAN, j = task % NSPAN;
    int s0, s1, row;
    if (j == 0)      { s0 = h_span[b*2]; s1 = h_span[b*2+1]; row = b; }
    else if (j == 1) { s0 = t_span[b*2]; s1 = t_span[b*2+1]; row = B + b; }
    else {
        int k = j - 2;
        s0 = b_spans[(b*K+k)*2]; s1 = b_spans[(b*K+k)*2 + 1];
        row = 2*B + b*K + k;
    }
    int nch = S / rpc;
    int c0 = s0 / rpc, c1 = s1 / rpc;
    int t = threadIdx.x;
    float4 m = make_float4(-INFINITY, -INFINITY, -INFINITY, -INFINITY);
    for (int c = c0; c <= c1; ++c) {
        float4 v = *(const float4*)(partial + (((size_t)(b*nch + c))*NSPAN + j) * D + t*4);
        m.x = fmaxf(m.x, v.x); m.y = fmaxf(m.y, v.y);
        m.z = fmaxf(m.z, v.z); m.w = fmaxf(m.w, v.w);
    }
    ((float4*)(pooled + (size_t)row * D))[t] = m;
}

// ---------------------------------------------------------------------------
// GEMM: p_part[ks][m][e] = sum_{d in ks-range} pooled[m][d] * W_m[e][d]
// 64x64 tiles, 4x4 register tiles, both operands staged transposed in LDS.
// grid = (12, 10, KSPLIT), block = 256.
// ---------------------------------------------------------------------------
template<int KSPLIT>
__global__ void k_gemm(const float* __restrict__ pooled,
                       const float* __restrict__ wu,
                       const float* __restrict__ wv,
                       const float* __restrict__ wi,
                       float* __restrict__ p_part) {
    __shared__ float At[16][68];
    __shared__ float Wt[16][68];
    int e0 = blockIdx.x * 64;
    int m0 = blockIdx.y * 64;
    const int klen = D / KSPLIT;
    int dbase = blockIdx.z * klen;
    const float* Wm = (m0 < B) ? wu : (m0 < 2*B) ? wv : wi;

    int tid = threadIdx.x;
    int tx = tid & 15, ty = tid >> 4;
    int lm = tid >> 2;
    int ld = (tid & 3) * 4;

    float acc[4][4] = {};
    const int kchunks = klen / 16;
    #pragma unroll 2
    for (int kc = 0; kc < kchunks; ++kc) {
        int d0 = dbase + kc * 16;
        float4 a4 = *(const float4*)(pooled + (size_t)(m0 + lm) * D + d0 + ld);
        float4 w4 = *(const float4*)(Wm     + (size_t)(e0 + lm) * D + d0 + ld);
        __syncthreads();
        At[ld+0][lm] = a4.x; At[ld+1][lm] = a4.y; At[ld+2][lm] = a4.z; At[ld+3][lm] = a4.w;
        Wt[ld+0][lm] = w4.x; Wt[ld+1][lm] = w4.y; Wt[ld+2][lm] = w4.z; Wt[ld+3][lm] = w4.w;
        __syncthreads();
        #pragma unroll
        for (int dd = 0; dd < 16; ++dd) {
            float4 av  = *(const float4*)&At[dd][ty << 2];
            float4 wvv = *(const float4*)&Wt[dd][tx << 2];
            float a_[4] = {av.x, av.y, av.z, av.w};
            float w_[4] = {wvv.x, wvv.y, wvv.z, wvv.w};
            #pragma unroll
            for (int i = 0; i < 4; ++i)
                #pragma unroll
                for (int jj = 0; jj < 4; ++jj)
                    acc[i][jj] += a_[i] * w_[jj];
        }
    }
    #pragma unroll
    for (int i = 0; i < 4; ++i) {
        float4 o = make_float4(acc[i][0], acc[i][1], acc[i][2], acc[i][3]);
        *(float4*)(p_part + ((size_t)blockIdx.z * M_TOT + m0 + ty*4 + i) * D + e0 + tx*4) = o;
    }
}

// ---------------------------------------------------------------------------
// Attention + s = u + v + ctx. One block per b, 256 threads.
// ---------------------------------------------------------------------------
template<int KSPLIT>
__global__ void k_att(const float* __restrict__ p_part,
                      const float* __restrict__ wu_b,
                      const float* __restrict__ wv_b,
                      const float* __restrict__ wi_b,
                      float* __restrict__ s_out) {
    __shared__ float U[D], V[D], BI[K][D];
    __shared__ float dots[K];
    int b = blockIdx.x, tid = threadIdx.x;

    if (tid < 192) {
        int t = tid;
        float4 su = *(const float4*)(wu_b + t*4);
        float4 sv = *(const float4*)(wv_b + t*4);
        #pragma unroll
        for (int ks = 0; ks < KSPLIT; ++ks) {
            float4 pu = *(const float4*)(p_part + ((size_t)ks * M_TOT + b)     * D + t*4);
            float4 pv = *(const float4*)(p_part + ((size_t)ks * M_TOT + B + b) * D + t*4);
            su.x += pu.x; su.y += pu.y; su.z += pu.z; su.w += pu.w;
            sv.x += pv.x; sv.y += pv.y; sv.z += pv.z; sv.w += pv.w;
        }
        *(float4*)&U[t*4] = su;
        *(float4*)&V[t*4] = sv;
        #pragma unroll
        for (int k = 0; k < K; ++k) {
            float4 sb = *(const float4*)(wi_b + t*4);
            #pragma unroll
            for (int ks = 0; ks < KSPLIT; ++ks) {
                float4 pb = *(const float4*)(p_part + ((size_t)ks * M_TOT + 2*B + b*K + k) * D + t*4);
                sb.x += pb.x; sb.y += pb.y; sb.z += pb.z; sb.w += pb.w;
            }
            *(float4*)&BI[k][t*4] = sb;
        }
    }
    __syncthreads();

    int wave = tid >> 6, lane = tid & 63;
    for (int kk = 0; kk < 2; ++kk) {
        int k = wave * 2 + kk;
        float part = 0.f;
        for (int d = lane; d < D; d += 64) part += U[d] * BI[k][d];
        #pragma unroll
        for (int off = 32; off > 0; off >>= 1) part += __shfl_down(part, off);
        if (lane == 0) dots[k] = part * 0.125f;   // 1/sqrt(D_K=64)
    }
    __syncthreads();

    float mx = -INFINITY;
    #pragma unroll
    for (int k = 0; k < K; ++k) mx = fmaxf(mx, dots[k]);
    float ex[K], sum = 0.f;
    #pragma unroll
    for (int k = 0; k < K; ++k) { ex[k] = expf(dots[k] - mx); sum += ex[k]; }
    float inv = 1.f / sum;

    for (int d = tid; d < D; d += 256) {
        float c = 0.f;
        #pragma unroll
        for (int k = 0; k < K; ++k) c += ex[k] * BI[k][d];
        s_out[(size_t)b * D + d] = U[d] + V[d] + c * inv;
    }
}

// ---------------------------------------------------------------------------
// pair = relu(s @ ln1_w^T + ln1_b). grid (3, 64), 256 thr, 1 out/thr.
// ---------------------------------------------------------------------------
__global__ void k_pair(const float* __restrict__ s,
                       const float* __restrict__ ln1_w,
                       const float* __restrict__ ln1_b,
                       float* __restrict__ pair) {
    __shared__ float Sv[D];
    int b = blockIdx.y, e0 = blockIdx.x * 256, tid = threadIdx.x;
    for (int d = tid; d < D; d += 256) Sv[d] = s[(size_t)b * D + d];
    __syncthreads();
    int e = e0 + tid;
    const float* wr = ln1_w + (size_t)e * D;
    float acc = 0.f;
    for (int d = 0; d < D; d += 4) {
        float4 s4 = *(const float4*)&Sv[d];
        float4 w4 = *(const float4*)(wr + d);
        acc += s4.x*w4.x + s4.y*w4.y + s4.z*w4.z + s4.w*w4.w;
    }
    pair[(size_t)b * D + e] = fmaxf(acc + ln1_b[e], 0.f);
}

// ---------------------------------------------------------------------------
// logits = pair @ pred_w^T + pred_b. One block per b, 320 thr.
// ---------------------------------------------------------------------------
__global__ void k_pred(const float* __restrict__ pair,
                       const float* __restrict__ pred_w,
                       const float* __restrict__ pred_b,
                       float* __restrict__ out) {
    __shared__ float P[D];
    int b = blockIdx.x, tid = threadIdx.x;
    for (int d = tid; d < D; d += 320) P[d] = pair[(size_t)b * D + d];
    __syncthreads();
    if (tid < R) {
        const float* wr = pred_w + (size_t)tid * D;
        float acc = 0.f;
        for (int d = 0; d < D; d += 4) {
            float4 p4 = *(const float4*)&P[d];
            float4 w4 = *(const float4*)(wr + d);
            acc += p4.x*w4.x + p4.y*w4.y + p4.z*w4.z + p4.w*w4.w;
        }
        out[(size_t)b * R + tid] = acc + pred_b[tid];
    }
}

// ---------------------------------------------------------------------------
extern "C" void kernel_launch(void* const* d_in, const int* in_sizes, int n_in,
                              void* d_out, int out_size, void* d_ws, size_t ws_size,
                              hipStream_t stream) {
    const float* emb     = (const float*)d_in[0];
    const int*   h_span  = (const int*)  d_in[1];
    const int*   t_span  = (const int*)  d_in[2];
    const int*   b_spans = (const int*)  d_in[3];
    const float* wu_w    = (const float*)d_in[4];
    const float* wu_b    = (const float*)d_in[5];
    const float* wv_w    = (const float*)d_in[6];
    const float* wv_b    = (const float*)d_in[7];
    const float* wi_w    = (const float*)d_in[8];
    const float* wi_b    = (const float*)d_in[9];
    const float* ln1_w   = (const float*)d_in[10];
    const float* ln1_b   = (const float*)d_in[11];
    const float* pred_w  = (const float*)d_in[12];
    const float* pred_b  = (const float*)d_in[13];
    float* out = (float*)d_out;

    const int KSPLIT = 4;
    size_t avail = ws_size / sizeof(float);
    auto need = [&](int nch_) -> size_t {
        return (size_t)M_TOT*D + (size_t)KSPLIT*M_TOT*D + 2*(size_t)B*D
             + (size_t)B*nch_*NSPAN*D;
    };
    int nch = (need(32) <= avail) ? 32 : 16;   // ws is ~400 MB; 32 needs 73 MB

    float* ws      = (float*)d_ws;
    float* pooled  = ws;                                   // M_TOT*D
    float* p_part  = pooled + (size_t)M_TOT * D;           // KSPLIT*M_TOT*D
    float* s_buf   = p_part + (size_t)KSPLIT * M_TOT * D;  // B*D
    float* pair    = s_buf + (size_t)B * D;                // B*D
    float* partial = pair + (size_t)B * D;                 // B*nch*NSPAN*D

    if (nch == 32)
        k_pool1<16><<<dim3(B, 32), 192, 0, stream>>>(emb, h_span, t_span, b_spans, partial);
    else
        k_pool1<32><<<dim3(B, 16), 192, 0, stream>>>(emb, h_span, t_span, b_spans, partial);
    k_pool2<<<M_TOT, 192, 0, stream>>>(partial, h_span, t_span, b_spans, pooled, S / nch);
    k_gemm<KSPLIT><<<dim3(D/64, M_TOT/64, KSPLIT), 256, 0, stream>>>(pooled, wu_w, wv_w, wi_w, p_part);
    k_att<KSPLIT><<<B, 256, 0, stream>>>(p_part, wu_b, wv_b, wi_b, s_buf);
    k_pair<<<dim3(D/256, B), 256, 0, stream>>>(s_buf, ln1_w, ln1_b, pair);
    k_pred<<<B, 320, 0, stream>>>(pair, pred_w, pred_b, out);
}